// Round 1
// baseline (1271.417 us; speedup 1.0000x reference)
//
#include <hip/hip_runtime.h>

#define NN 50000
#define NE 300000
#define INDIM 2000
#define KPAD 2048

typedef float f32x4 __attribute__((ext_vector_type(4)));
typedef __bf16 bf16x8 __attribute__((ext_vector_type(8)));
typedef unsigned short u16x8 __attribute__((ext_vector_type(8)));

__device__ __forceinline__ unsigned short f2bf(float f) {
  union { float f; unsigned u; } v; v.f = f;
  unsigned r = v.u + 0x7FFFu + ((v.u >> 16) & 1u);
  return (unsigned short)(r >> 16);
}
__device__ __forceinline__ float bf2f(unsigned short h) {
  union { unsigned u; float f; } v; v.u = ((unsigned)h) << 16;
  return v.f;
}

// ---------- weight prep: transpose+bf16 weights, build per-node MLP matrix ----------
__global__ __launch_bounds__(256) void prep_kernel(
    const float* __restrict__ Wh, const float* __restrict__ g1,
    const float* __restrict__ g2, const float* __restrict__ W1,
    unsigned short* __restrict__ WhT, unsigned short* __restrict__ g1T,
    unsigned short* __restrict__ g2T, float* __restrict__ Wc)
{
  int i = blockIdx.x * 256 + threadIdx.x;
  if (i < 128 * KPAD) {                      // WhT[128][2048] (K zero-padded)
    int n = i >> 11, k = i & (KPAD - 1);
    WhT[i] = (k < INDIM) ? f2bf(Wh[(size_t)k * 128 + n]) : (unsigned short)0;
    return;
  }
  i -= 128 * KPAD;
  if (i < 256 * 128) {                       // g1T[256][128]
    int n = i >> 7, k = i & 127;
    g1T[i] = f2bf(g1[(size_t)k * 256 + n]);
    return;
  }
  i -= 256 * 128;
  if (i < 128 * 256) {                       // g2T[128][256]
    int n = i >> 8, k = i & 255;
    g2T[i] = f2bf(g2[(size_t)k * 128 + n]);
    return;
  }
  i -= 128 * 256;
  if (i < 2048) {                            // Wc[128][16]: cols 0-7 = W1[:128], 8-15 = W1[128:]
    int f = i >> 4, o = i & 15;
    int k = (o & 7) >> 1, h = o & 1;
    int fr = (o < 8) ? f : (128 + f);
    Wc[i] = W1[(size_t)k * 512 + fr * 2 + h];
  }
}

// ---------- generic bf16 MFMA GEMM: C[M,N] = A[M,Ka] * BT[N,Kb]^T (+bias,relu), C bf16 ----------
template<int A_F32, int BIAS, int RELU>
__global__ __launch_bounds__(256) void gemm_kernel(
    const void* __restrict__ Aptr, const unsigned short* __restrict__ BT,
    unsigned short* __restrict__ C, const float* __restrict__ bias,
    int M, int N, int Ka, int Kb, int nkb)
{
  __shared__ unsigned short Alds[128 * 64];
  __shared__ unsigned short Blds[128 * 64];
  const int tid = threadIdx.x, lane = tid & 63, wv = tid >> 6;
  const int mBase = blockIdx.x * 128, nBase = blockIdx.y * 128;
  const int wrow = (wv >> 1) * 64, wcol = (wv & 1) * 64;
  const int lr = lane >> 3, lk8 = (lane & 7) * 8;
  f32x4 acc[4][4] = {};

  for (int kb = 0; kb < nkb; ++kb) {
    int k0 = kb * 64;
    #pragma unroll
    for (int i = 0; i < 4; ++i) {            // stage B tile [128][64]
      int chunk = wv * 4 + i;
      int brow = chunk * 8 + lr;
      u16x8 v = *(const u16x8*)(BT + (size_t)(nBase + brow) * Kb + k0 + lk8);
      *(u16x8*)&Blds[chunk * 512 + lane * 8] = v;
    }
    #pragma unroll
    for (int i = 0; i < 4; ++i) {            // stage A tile [128][64] (fp32->bf16 if A_F32)
      int chunk = wv * 4 + i;
      int arow = chunk * 8 + lr;
      int rg = mBase + arow; if (rg > M - 1) rg = M - 1;
      u16x8 v;
      if (A_F32) {
        const float* Af = (const float*)Aptr;
        int kc = k0 + lk8; if (kc > Ka - 8) kc = Ka - 8;   // stay in-bounds; pad cols hit zero B
        const float4* s = (const float4*)(Af + (size_t)rg * Ka + kc);
        float4 f0 = s[0], f1 = s[1];
        v[0]=f2bf(f0.x); v[1]=f2bf(f0.y); v[2]=f2bf(f0.z); v[3]=f2bf(f0.w);
        v[4]=f2bf(f1.x); v[5]=f2bf(f1.y); v[6]=f2bf(f1.z); v[7]=f2bf(f1.w);
      } else {
        const unsigned short* Ab = (const unsigned short*)Aptr;
        v = *(const u16x8*)(Ab + (size_t)rg * Ka + k0 + lk8);
      }
      *(u16x8*)&Alds[chunk * 512 + lane * 8] = v;
    }
    __syncthreads();
    #pragma unroll
    for (int kk = 0; kk < 2; ++kk) {
      const int ko = kk * 32 + (lane >> 4) * 8;
      const int r16 = lane & 15;
      bf16x8 a[4], b[4];
      #pragma unroll
      for (int mf = 0; mf < 4; ++mf)
        a[mf] = __builtin_bit_cast(bf16x8, *(const u16x8*)&Alds[(wrow + mf*16 + r16) * 64 + ko]);
      #pragma unroll
      for (int nf = 0; nf < 4; ++nf)
        b[nf] = __builtin_bit_cast(bf16x8, *(const u16x8*)&Blds[(wcol + nf*16 + r16) * 64 + ko]);
      #pragma unroll
      for (int mf = 0; mf < 4; ++mf)
        #pragma unroll
        for (int nf = 0; nf < 4; ++nf)
          acc[mf][nf] = __builtin_amdgcn_mfma_f32_16x16x32_bf16(a[mf], b[nf], acc[mf][nf], 0, 0, 0);
    }
    __syncthreads();
  }

  const int r16 = lane & 15, r4 = (lane >> 4) * 4;
  #pragma unroll
  for (int mf = 0; mf < 4; ++mf) {
    #pragma unroll
    for (int j = 0; j < 4; ++j) {
      int row = mBase + wrow + mf * 16 + r4 + j;
      if (row < M) {
        #pragma unroll
        for (int nf = 0; nf < 4; ++nf) {
          int col = nBase + wcol + nf * 16 + r16;
          float vv = acc[mf][nf][j];
          if (BIAS) vv += bias[col];
          if (RELU) vv = vv > 0.f ? vv : 0.f;
          C[(size_t)row * N + col] = f2bf(vv);
        }
      }
    }
  }
}

// ---------- P[n][16] = h0[n] . Wc  (per-node halves of the edge MLP) ----------
__global__ __launch_bounds__(256) void p_kernel(const unsigned short* __restrict__ h0,
    const float* __restrict__ Wc, float* __restrict__ P)
{
  __shared__ float wl[2048];
  for (int i = threadIdx.x; i < 2048; i += 256) wl[i] = Wc[i];
  __syncthreads();
  int n = blockIdx.x * 256 + threadIdx.x;
  if (n >= NN) return;
  const unsigned short* hr = h0 + (size_t)n * 128;
  float acc[16];
  #pragma unroll
  for (int o = 0; o < 16; ++o) acc[o] = 0.f;
  for (int f8 = 0; f8 < 128; f8 += 8) {
    u16x8 hv = *(const u16x8*)(hr + f8);
    #pragma unroll
    for (int j = 0; j < 8; ++j) {
      float v = bf2f(hv[j]);
      #pragma unroll
      for (int o = 0; o < 16; ++o) acc[o] += v * wl[(f8 + j) * 16 + o];
    }
  }
  #pragma unroll
  for (int o = 0; o < 16; ++o) P[(size_t)n * 16 + o] = acc[o];
}

// ---------- init scratch ----------
__global__ __launch_bounds__(256) void init_kernel(float* deg, int* hist, float* colsum)
{
  int i = blockIdx.x * 256 + threadIdx.x;
  if (i < 4 * NN) deg[i] = 1.0f;           // self-loop weight
  if (i < NN) hist[i] = 0;
  if (i < 512) colsum[i] = 0.f;
}

// ---------- edge MLP: Gk + degree accumulation + dst histogram ----------
__global__ __launch_bounds__(256) void gk_kernel(
    const int* __restrict__ ei, const float* __restrict__ P,
    const float* __restrict__ b1, const float* __restrict__ W2,
    const float* __restrict__ b2, float* __restrict__ GkOut,
    float* __restrict__ deg, int* __restrict__ hist)
{
  int e = blockIdx.x * 256 + threadIdx.x;
  if (e >= NE) return;
  int s = ei[e], d = ei[NE + e];
  const float4* Ps = (const float4*)(P + (size_t)s * 16);
  const float4* Pd = (const float4*)(P + (size_t)d * 16);
  float4 p1a = Ps[0], p1b = Ps[1];
  float4 p2a = Pd[2], p2b = Pd[3];
  float p1[8] = {p1a.x, p1a.y, p1a.z, p1a.w, p1b.x, p1b.y, p1b.z, p1b.w};
  float p2[8] = {p2a.x, p2a.y, p2a.z, p2a.w, p2b.x, p2b.y, p2b.z, p2b.w};
  #pragma unroll
  for (int k = 0; k < 4; ++k) {
    float h0v = p1[2*k]   + p2[2*k]   + b1[2*k];
    float h1v = p1[2*k+1] + p2[2*k+1] + b1[2*k+1];
    h0v = h0v > 0.f ? h0v : 0.f;
    h1v = h1v > 0.f ? h1v : 0.f;
    float pre = h0v * W2[2*k] + h1v * W2[2*k+1] + b2[k];
    float g = 1.f / (1.f + expf(-pre));
    GkOut[(size_t)k * NE + e] = g;
    atomicAdd(&deg[k * NN + d], g);
  }
  atomicAdd(&hist[d], 1);
}

// ---------- 3-phase exclusive scan over hist[50000] ----------
__global__ __launch_bounds__(256) void scan1_kernel(const int* __restrict__ hist,
    int* __restrict__ excl, int* __restrict__ bsum)
{
  __shared__ int sm[256];
  int t = threadIdx.x, i = blockIdx.x * 256 + t;
  int v = (i < NN) ? hist[i] : 0;
  sm[t] = v;
  __syncthreads();
  for (int off = 1; off < 256; off <<= 1) {
    int y = (t >= off) ? sm[t - off] : 0;
    __syncthreads();
    sm[t] += y;
    __syncthreads();
  }
  if (i < NN) excl[i] = sm[t] - v;
  if (t == 255) bsum[blockIdx.x] = sm[255];
}

__global__ __launch_bounds__(256) void scan2_kernel(int* bsum, int nb)
{
  __shared__ int sm[256];
  int t = threadIdx.x;
  int v = (t < nb) ? bsum[t] : 0;
  sm[t] = v;
  __syncthreads();
  for (int off = 1; off < 256; off <<= 1) {
    int y = (t >= off) ? sm[t - off] : 0;
    __syncthreads();
    sm[t] += y;
    __syncthreads();
  }
  if (t < nb) bsum[t] = sm[t] - v;   // exclusive offsets, in place
}

__global__ __launch_bounds__(256) void scan3_kernel(int* __restrict__ rowstart,
    const int* __restrict__ bsum, int* __restrict__ cursor)
{
  int i = blockIdx.x * 256 + threadIdx.x;
  if (i < NN) {
    int v = rowstart[i] + bsum[blockIdx.x];
    rowstart[i] = v;
    cursor[i] = v;
  }
  if (i == 0) rowstart[NN] = NE;
}

__global__ __launch_bounds__(256) void dinv_kernel(const float* __restrict__ deg,
    float* __restrict__ dinv)
{
  int i = blockIdx.x * 256 + threadIdx.x;
  if (i < 4 * NN) dinv[i] = rsqrtf(deg[i]);
}

// ---------- CSR scatter (counting sort by dst) ----------
__global__ __launch_bounds__(256) void csr_kernel(const int* __restrict__ ei,
    int* __restrict__ cursor, int* __restrict__ csr_s, int* __restrict__ csr_e)
{
  int e = blockIdx.x * 256 + threadIdx.x;
  if (e >= NE) return;
  int s = ei[e], d = ei[NE + e];
  int pos = atomicAdd(&cursor[d], 1);
  csr_s[pos] = s;
  csr_e[pos] = e;
}

// ---------- per-slot {src, Gk*dinv[src]} pairs for all 4 k ----------
__global__ __launch_bounds__(256) void csrw_kernel(const int* __restrict__ csr_s,
    const int* __restrict__ csr_e, const float* __restrict__ Gk,
    const float* __restrict__ dinv, int2* __restrict__ csw)
{
  int p = blockIdx.x * 256 + threadIdx.x;
  if (p >= NE) return;
  int s = csr_s[p], e = csr_e[p];
  #pragma unroll
  for (int k = 0; k < 4; ++k) {
    float w = Gk[(size_t)k * NE + e] * dinv[k * NN + s];
    int2 v; v.x = s; v.y = __float_as_int(w);
    csw[(size_t)k * NE + p] = v;
  }
}

// ---------- GCN aggregation: one wave per dst node, 2 cols/lane ----------
// SUMMODE=0: Hout[n] = dinv[n]*(sum_w h[src] + dinv[n]*h[n])           (bf16 out)
// SUMMODE=1: z = relu(same + bias); colsum += z (nothing stored per node)
template<int SUMMODE>
__global__ __launch_bounds__(256) void agg_kernel(
    const unsigned short* __restrict__ Hin, unsigned short* __restrict__ Hout,
    const float* __restrict__ dinvk, const int* __restrict__ rowstart,
    const int2* __restrict__ csw, const float* __restrict__ bias,
    float* __restrict__ colsum)
{
  const int lane = threadIdx.x & 63;
  const int wv = threadIdx.x >> 6;
  const int gw = blockIdx.x * 4 + wv;
  const int nw = gridDim.x * 4;
  const int c0 = lane * 2;
  float s0 = 0.f, s1 = 0.f;
  float bb0 = 0.f, bb1 = 0.f;
  if (SUMMODE) { bb0 = bias[c0]; bb1 = bias[c0 + 1]; }
  for (int n = gw; n < NN; n += nw) {
    float dd = dinvk[n];
    unsigned selfv = *(const unsigned*)(Hin + (size_t)n * 128 + c0);
    float a0 = dd * bf2f((unsigned short)(selfv & 0xFFFFu));
    float a1 = dd * bf2f((unsigned short)(selfv >> 16));
    int rs = rowstart[n], re = rowstart[n + 1];
    for (int p = rs; p < re; ++p) {
      int2 sw = csw[p];
      float w = __int_as_float(sw.y);
      unsigned hv = *(const unsigned*)(Hin + (size_t)sw.x * 128 + c0);
      a0 += w * bf2f((unsigned short)(hv & 0xFFFFu));
      a1 += w * bf2f((unsigned short)(hv >> 16));
    }
    a0 *= dd; a1 *= dd;
    if (SUMMODE) {
      a0 += bb0; a1 += bb1;
      a0 = a0 > 0.f ? a0 : 0.f;
      a1 = a1 > 0.f ? a1 : 0.f;
      s0 += a0; s1 += a1;
    } else {
      unsigned ov = (unsigned)f2bf(a0) | ((unsigned)f2bf(a1) << 16);
      *(unsigned*)(Hout + (size_t)n * 128 + c0) = ov;
    }
  }
  if (SUMMODE) {
    __shared__ float lsum[128];
    if (threadIdx.x < 128) lsum[threadIdx.x] = 0.f;
    __syncthreads();
    atomicAdd(&lsum[c0], s0);
    atomicAdd(&lsum[c0 + 1], s1);
    __syncthreads();
    if (threadIdx.x < 128) atomicAdd(&colsum[threadIdx.x], lsum[threadIdx.x]);
  }
}

// ---------- descriptors[k][o] = mean(z2) . fc_W + fc_b ----------
__global__ void desc_kernel(const float* __restrict__ colsum,
    const float* __restrict__ fcW, const float* __restrict__ fcb,
    float* __restrict__ out)
{
  int t = threadIdx.x;
  if (t >= 128) return;
  int k = t >> 5, o = t & 31;
  float acc = 0.f;
  for (int c = 0; c < 128; ++c)
    acc += colsum[k * 128 + c] * fcW[c * 32 + o];
  out[t] = acc * (1.f / (float)NN) + fcb[o];
}

extern "C" void kernel_launch(void* const* d_in, const int* in_sizes, int n_in,
                              void* d_out, int out_size, void* d_ws, size_t ws_size,
                              hipStream_t stream)
{
  (void)in_sizes; (void)n_in; (void)out_size; (void)ws_size;
  const float* X   = (const float*)d_in[0];
  const int*   ei  = (const int*)d_in[1];
  const float* Wh  = (const float*)d_in[2];
  const float* W1  = (const float*)d_in[3];
  const float* b1  = (const float*)d_in[4];
  const float* W2  = (const float*)d_in[5];
  const float* b2  = (const float*)d_in[6];
  const float* g1W = (const float*)d_in[7];
  const float* g1b = (const float*)d_in[8];
  const float* g2W = (const float*)d_in[9];
  const float* g2b = (const float*)d_in[10];
  const float* fcW = (const float*)d_in[11];
  const float* fcb = (const float*)d_in[12];
  float* out = (float*)d_out;

  char* ws = (char*)d_ws;
  size_t off = 0;
  auto alloc = [&](size_t bytes) -> void* {
    void* p = ws + off; off += (bytes + 255) & ~(size_t)255; return p;
  };
  unsigned short* WhT = (unsigned short*)alloc((size_t)128 * KPAD * 2);
  unsigned short* g1T = (unsigned short*)alloc((size_t)256 * 128 * 2);
  unsigned short* g2T = (unsigned short*)alloc((size_t)128 * 256 * 2);
  float* Wc  = (float*)alloc(2048 * 4);
  unsigned short* h0 = (unsigned short*)alloc((size_t)NN * 128 * 2);
  float* P   = (float*)alloc((size_t)NN * 16 * 4);
  float* deg = (float*)alloc((size_t)4 * NN * 4);
  float* dinv= (float*)alloc((size_t)4 * NN * 4);
  int* hist  = (int*)alloc((size_t)NN * 4);
  int* rowst = (int*)alloc((size_t)(NN + 1) * 4);
  int* cursor= (int*)alloc((size_t)NN * 4);
  int* bsum  = (int*)alloc(256 * 4);
  int* csr_s = (int*)alloc((size_t)NE * 4);
  int* csr_e = (int*)alloc((size_t)NE * 4);
  int2* csw  = (int2*)alloc((size_t)4 * NE * 8);
  unsigned short* A1 = (unsigned short*)alloc((size_t)NN * 128 * 2);
  unsigned short* Z1 = (unsigned short*)alloc((size_t)NN * 256 * 2);
  unsigned short* Y2 = (unsigned short*)alloc((size_t)NN * 128 * 2);
  float* colsum = (float*)alloc(512 * 4);

  float* GkOut = out + 128;
  const int gEdge = (NE + 255) / 256;

  prep_kernel<<<(128*KPAD + 256*128 + 128*256 + 2048 + 255)/256, 256, 0, stream>>>(
      Wh, g1W, g2W, W1, WhT, g1T, g2T, Wc);
  gemm_kernel<1,0,0><<<dim3(391, 1), 256, 0, stream>>>(
      X, WhT, h0, nullptr, NN, 128, INDIM, KPAD, KPAD / 64);
  p_kernel<<<196, 256, 0, stream>>>(h0, Wc, P);
  init_kernel<<<(4*NN + 255)/256, 256, 0, stream>>>(deg, hist, colsum);
  gk_kernel<<<gEdge, 256, 0, stream>>>(ei, P, b1, W2, b2, GkOut, deg, hist);
  scan1_kernel<<<196, 256, 0, stream>>>(hist, rowst, bsum);
  scan2_kernel<<<1, 256, 0, stream>>>(bsum, 196);
  scan3_kernel<<<196, 256, 0, stream>>>(rowst, bsum, cursor);
  dinv_kernel<<<(4*NN + 255)/256, 256, 0, stream>>>(deg, dinv);
  csr_kernel<<<gEdge, 256, 0, stream>>>(ei, cursor, csr_s, csr_e);
  csrw_kernel<<<gEdge, 256, 0, stream>>>(csr_s, csr_e, GkOut, dinv, csw);

  for (int k = 0; k < 4; ++k) {
    agg_kernel<0><<<2048, 256, 0, stream>>>(
        h0, A1, dinv + k * NN, rowst, csw + (size_t)k * NE, nullptr, nullptr);
    gemm_kernel<0,1,1><<<dim3(391, 2), 256, 0, stream>>>(
        A1, g1T, Z1, g1b, NN, 256, 128, 128, 2);
    gemm_kernel<0,0,0><<<dim3(391, 1), 256, 0, stream>>>(
        Z1, g2T, Y2, nullptr, NN, 128, 256, 256, 4);
    agg_kernel<1><<<2048, 256, 0, stream>>>(
        Y2, nullptr, dinv + k * NN, rowst, csw + (size_t)k * NE, g2b, colsum + k * 128);
  }
  desc_kernel<<<1, 128, 0, stream>>>(colsum, fcW, fcb, out);
}

// Round 3
// 943.368 us; speedup vs baseline: 1.3477x; 1.3477x over previous
//
#include <hip/hip_runtime.h>

#define NN 50000
#define NE 300000
#define INDIM 2000
#define KPAD 2048

typedef float f32x4 __attribute__((ext_vector_type(4)));
typedef __bf16 bf16x8 __attribute__((ext_vector_type(8)));
typedef unsigned short u16x8 __attribute__((ext_vector_type(8)));

__device__ __forceinline__ unsigned short f2bf(float f) {
  union { float f; unsigned u; } v; v.f = f;
  unsigned r = v.u + 0x7FFFu + ((v.u >> 16) & 1u);
  return (unsigned short)(r >> 16);
}
__device__ __forceinline__ float bf2f(unsigned short h) {
  union { unsigned u; float f; } v; v.u = ((unsigned)h) << 16;
  return v.f;
}

// ---------- weight prep: transpose+bf16 weights, build per-node MLP matrix ----------
__global__ __launch_bounds__(256) void prep_kernel(
    const float* __restrict__ Wh, const float* __restrict__ g1,
    const float* __restrict__ g2, const float* __restrict__ W1,
    unsigned short* __restrict__ WhT, unsigned short* __restrict__ g1T,
    unsigned short* __restrict__ g2T, float* __restrict__ Wc)
{
  int i = blockIdx.x * 256 + threadIdx.x;
  if (i < 128 * KPAD) {                      // WhT[128][2048] (K zero-padded)
    int n = i >> 11, k = i & (KPAD - 1);
    WhT[i] = (k < INDIM) ? f2bf(Wh[(size_t)k * 128 + n]) : (unsigned short)0;
    return;
  }
  i -= 128 * KPAD;
  if (i < 256 * 128) {                       // g1T[256][128]
    int n = i >> 7, k = i & 127;
    g1T[i] = f2bf(g1[(size_t)k * 256 + n]);
    return;
  }
  i -= 256 * 128;
  if (i < 128 * 256) {                       // g2T[128][256]
    int n = i >> 8, k = i & 255;
    g2T[i] = f2bf(g2[(size_t)k * 128 + n]);
    return;
  }
  i -= 128 * 256;
  if (i < 2048) {                            // Wc[128][16]: cols 0-7 = W1[:128], 8-15 = W1[128:]
    int f = i >> 4, o = i & 15;
    int k = (o & 7) >> 1, h = o & 1;
    int fr = (o < 8) ? f : (128 + f);
    Wc[i] = W1[(size_t)k * 512 + fr * 2 + h];
  }
}

// ---------- bf16 MFMA GEMM with XOR-swizzled LDS (T2): C[M,N] = A[M,Ka]*BT[N,Kb]^T ----------
template<int A_F32>
__global__ __launch_bounds__(256) void gemm_kernel(
    const void* __restrict__ Aptr, const unsigned short* __restrict__ BT,
    unsigned short* __restrict__ C, int M, int N, int Ka, int Kb, int nkb)
{
  __shared__ unsigned short Alds[128 * 64];
  __shared__ unsigned short Blds[128 * 64];
  const int tid = threadIdx.x, lane = tid & 63, wv = tid >> 6;
  const int mBase = blockIdx.x * 128, nBase = blockIdx.y * 128;
  const int wrow = (wv >> 1) * 64, wcol = (wv & 1) * 64;
  const int lr = lane >> 3, lk8 = (lane & 7) * 8;
  // swizzled LDS store index (shorts): row-major [128][64] with 16B-slot XOR by row&7
  const int stIdx = (lr) * 64 + (((lane & 7) ^ lr) << 3);
  f32x4 acc[4][4] = {};

  for (int kb = 0; kb < nkb; ++kb) {
    int k0 = kb * 64;
    #pragma unroll
    for (int i = 0; i < 4; ++i) {            // stage B tile [128][64]
      int chunk = wv * 4 + i;
      int brow = chunk * 8 + lr;
      u16x8 v = *(const u16x8*)(BT + (size_t)(nBase + brow) * Kb + k0 + lk8);
      *(u16x8*)&Blds[chunk * 512 + stIdx] = v;
    }
    #pragma unroll
    for (int i = 0; i < 4; ++i) {            // stage A tile [128][64] (fp32->bf16 if A_F32)
      int chunk = wv * 4 + i;
      int arow = chunk * 8 + lr;
      int rg = mBase + arow; if (rg > M - 1) rg = M - 1;
      u16x8 v;
      if (A_F32) {
        const float* Af = (const float*)Aptr;
        int kc = k0 + lk8; if (kc > Ka - 8) kc = Ka - 8;   // clamp; pad cols hit zero B
        const float4* s = (const float4*)(Af + (size_t)rg * Ka + kc);
        float4 f0 = s[0], f1 = s[1];
        v[0]=f2bf(f0.x); v[1]=f2bf(f0.y); v[2]=f2bf(f0.z); v[3]=f2bf(f0.w);
        v[4]=f2bf(f1.x); v[5]=f2bf(f1.y); v[6]=f2bf(f1.z); v[7]=f2bf(f1.w);
      } else {
        const unsigned short* Ab = (const unsigned short*)Aptr;
        v = *(const u16x8*)(Ab + (size_t)rg * Ka + k0 + lk8);
      }
      *(u16x8*)&Alds[chunk * 512 + stIdx] = v;
    }
    __syncthreads();
    #pragma unroll
    for (int kk = 0; kk < 2; ++kk) {
      const int r16 = lane & 15;
      const int slot = kk * 4 + (lane >> 4);          // 16B slot index 0..7
      bf16x8 a[4], b[4];
      #pragma unroll
      for (int mf = 0; mf < 4; ++mf) {
        int row = wrow + mf * 16 + r16;
        a[mf] = __builtin_bit_cast(bf16x8,
            *(const u16x8*)&Alds[row * 64 + ((slot ^ (row & 7)) << 3)]);
      }
      #pragma unroll
      for (int nf = 0; nf < 4; ++nf) {
        int row = wcol + nf * 16 + r16;
        b[nf] = __builtin_bit_cast(bf16x8,
            *(const u16x8*)&Blds[row * 64 + ((slot ^ (row & 7)) << 3)]);
      }
      #pragma unroll
      for (int mf = 0; mf < 4; ++mf)
        #pragma unroll
        for (int nf = 0; nf < 4; ++nf)
          acc[mf][nf] = __builtin_amdgcn_mfma_f32_16x16x32_bf16(a[mf], b[nf], acc[mf][nf], 0, 0, 0);
    }
    __syncthreads();
  }

  const int r16 = lane & 15, r4 = (lane >> 4) * 4;
  #pragma unroll
  for (int mf = 0; mf < 4; ++mf) {
    #pragma unroll
    for (int j = 0; j < 4; ++j) {
      int row = mBase + wrow + mf * 16 + r4 + j;
      if (row < M) {
        #pragma unroll
        for (int nf = 0; nf < 4; ++nf) {
          int col = nBase + wcol + nf * 16 + r16;
          C[(size_t)row * N + col] = f2bf(acc[mf][nf][j]);
        }
      }
    }
  }
}

// ---------- P[n][16] = h0[n] . Wc ----------
__global__ __launch_bounds__(256) void p_kernel(const unsigned short* __restrict__ h0,
    const float* __restrict__ Wc, float* __restrict__ P)
{
  __shared__ float wl[2048];
  for (int i = threadIdx.x; i < 2048; i += 256) wl[i] = Wc[i];
  __syncthreads();
  int n = blockIdx.x * 256 + threadIdx.x;
  if (n >= NN) return;
  const unsigned short* hr = h0 + (size_t)n * 128;
  float acc[16];
  #pragma unroll
  for (int o = 0; o < 16; ++o) acc[o] = 0.f;
  for (int f8 = 0; f8 < 128; f8 += 8) {
    u16x8 hv = *(const u16x8*)(hr + f8);
    #pragma unroll
    for (int j = 0; j < 8; ++j) {
      float v = bf2f(hv[j]);
      #pragma unroll
      for (int o = 0; o < 16; ++o) acc[o] += v * wl[(f8 + j) * 16 + o];
    }
  }
  #pragma unroll
  for (int o = 0; o < 16; ++o) P[(size_t)n * 16 + o] = acc[o];
}

__global__ __launch_bounds__(256) void init_kernel(float* deg, int* hist, float* colsum)
{
  int i = blockIdx.x * 256 + threadIdx.x;
  if (i < 4 * NN) deg[i] = 1.0f;           // self-loop weight
  if (i < NN) hist[i] = 0;
  if (i < 512) colsum[i] = 0.f;
}

// ---------- edge MLP: Gk (k-major for d_out, float4 per-edge for csrw) + deg + hist ----------
__global__ __launch_bounds__(256) void gk_kernel(
    const int* __restrict__ ei, const float* __restrict__ P,
    const float* __restrict__ b1, const float* __restrict__ W2,
    const float* __restrict__ b2, float* __restrict__ GkOut,
    float4* __restrict__ Gk4, float* __restrict__ deg, int* __restrict__ hist)
{
  int e = blockIdx.x * 256 + threadIdx.x;
  if (e >= NE) return;
  int s = ei[e], d = ei[NE + e];
  const float4* Ps = (const float4*)(P + (size_t)s * 16);
  const float4* Pd = (const float4*)(P + (size_t)d * 16);
  float4 p1a = Ps[0], p1b = Ps[1];
  float4 p2a = Pd[2], p2b = Pd[3];
  float p1[8] = {p1a.x, p1a.y, p1a.z, p1a.w, p1b.x, p1b.y, p1b.z, p1b.w};
  float p2[8] = {p2a.x, p2a.y, p2a.z, p2a.w, p2b.x, p2b.y, p2b.z, p2b.w};
  float g[4];
  #pragma unroll
  for (int k = 0; k < 4; ++k) {
    float h0v = p1[2*k]   + p2[2*k]   + b1[2*k];
    float h1v = p1[2*k+1] + p2[2*k+1] + b1[2*k+1];
    h0v = h0v > 0.f ? h0v : 0.f;
    h1v = h1v > 0.f ? h1v : 0.f;
    float pre = h0v * W2[2*k] + h1v * W2[2*k+1] + b2[k];
    g[k] = 1.f / (1.f + expf(-pre));
    GkOut[(size_t)k * NE + e] = g[k];
    atomicAdd(&deg[k * NN + d], g[k]);
  }
  Gk4[e] = make_float4(g[0], g[1], g[2], g[3]);
  atomicAdd(&hist[d], 1);
}

// ---------- 3-phase exclusive scan over hist[50000] ----------
__global__ __launch_bounds__(256) void scan1_kernel(const int* __restrict__ hist,
    int* __restrict__ excl, int* __restrict__ bsum)
{
  __shared__ int sm[256];
  int t = threadIdx.x, i = blockIdx.x * 256 + t;
  int v = (i < NN) ? hist[i] : 0;
  sm[t] = v;
  __syncthreads();
  for (int off = 1; off < 256; off <<= 1) {
    int y = (t >= off) ? sm[t - off] : 0;
    __syncthreads();
    sm[t] += y;
    __syncthreads();
  }
  if (i < NN) excl[i] = sm[t] - v;
  if (t == 255) bsum[blockIdx.x] = sm[255];
}

__global__ __launch_bounds__(256) void scan2_kernel(int* bsum, int nb)
{
  __shared__ int sm[256];
  int t = threadIdx.x;
  int v = (t < nb) ? bsum[t] : 0;
  sm[t] = v;
  __syncthreads();
  for (int off = 1; off < 256; off <<= 1) {
    int y = (t >= off) ? sm[t - off] : 0;
    __syncthreads();
    sm[t] += y;
    __syncthreads();
  }
  if (t < nb) bsum[t] = sm[t] - v;
}

__global__ __launch_bounds__(256) void scan3_kernel(int* __restrict__ rowstart,
    const int* __restrict__ bsum, int* __restrict__ cursor)
{
  int i = blockIdx.x * 256 + threadIdx.x;
  if (i < NN) {
    int v = rowstart[i] + bsum[blockIdx.x];
    rowstart[i] = v;
    cursor[i] = v;
  }
  if (i == 0) rowstart[NN] = NE;
}

__global__ __launch_bounds__(256) void dinv_kernel(const float* __restrict__ deg,
    float* __restrict__ dinv)
{
  int i = blockIdx.x * 256 + threadIdx.x;
  if (i < 4 * NN) dinv[i] = rsqrtf(deg[i]);
}

// ---------- CSR scatter (counting sort by dst) ----------
__global__ __launch_bounds__(256) void csr_kernel(const int* __restrict__ ei,
    int* __restrict__ cursor, int* __restrict__ csr_s, int* __restrict__ csr_e)
{
  int e = blockIdx.x * 256 + threadIdx.x;
  if (e >= NE) return;
  int s = ei[e], d = ei[NE + e];
  int pos = atomicAdd(&cursor[d], 1);
  csr_s[pos] = s;
  csr_e[pos] = e;
}

// ---------- per-slot weights for all 4 k: w4[p] = Gk[e] * dinv_k[src] ----------
__global__ __launch_bounds__(256) void csrw_kernel(const int* __restrict__ csr_s,
    const int* __restrict__ csr_e, const float4* __restrict__ Gk4,
    const float* __restrict__ dinv, float4* __restrict__ w4)
{
  int p = blockIdx.x * 256 + threadIdx.x;
  if (p >= NE) return;
  int s = csr_s[p], e = csr_e[p];
  float4 g = Gk4[e];
  float4 w;
  w.x = g.x * dinv[0 * NN + s];
  w.y = g.y * dinv[1 * NN + s];
  w.z = g.z * dinv[2 * NN + s];
  w.w = g.w * dinv[3 * NN + s];
  w4[p] = w;
}

// ---------- fused 4-k layer-1 aggregation on H1[NN,256] -> Z1all[4NN,256] (+b,relu) ----------
__global__ __launch_bounds__(256) void aggA_kernel(
    const unsigned short* __restrict__ H1, unsigned short* __restrict__ Z1,
    const float* __restrict__ dinv, const int* __restrict__ rowstart,
    const int* __restrict__ csr_s, const float4* __restrict__ w4,
    const float* __restrict__ g1b)
{
  const int lane = threadIdx.x & 63;
  const int wv = threadIdx.x >> 6;
  const int gw = blockIdx.x * 4 + wv;
  const int nw = gridDim.x * 4;
  const int c0 = lane * 4;
  float bb[4];
  #pragma unroll
  for (int c = 0; c < 4; ++c) bb[c] = g1b[c0 + c];
  for (int n = gw; n < NN; n += nw) {
    float dd[4];
    #pragma unroll
    for (int k = 0; k < 4; ++k) dd[k] = dinv[k * NN + n];
    uint2 sv = *(const uint2*)(H1 + (size_t)n * 256 + c0);
    float sf[4] = { bf2f((unsigned short)(sv.x & 0xFFFF)), bf2f((unsigned short)(sv.x >> 16)),
                    bf2f((unsigned short)(sv.y & 0xFFFF)), bf2f((unsigned short)(sv.y >> 16)) };
    float acc[4][4];
    #pragma unroll
    for (int k = 0; k < 4; ++k)
      #pragma unroll
      for (int c = 0; c < 4; ++c) acc[k][c] = dd[k] * sf[c];
    int rs = rowstart[n], re = rowstart[n + 1];
    for (int p = rs; p < re; ++p) {
      int s = csr_s[p];
      float4 w = w4[p];
      uint2 hv = *(const uint2*)(H1 + (size_t)s * 256 + c0);
      float hf[4] = { bf2f((unsigned short)(hv.x & 0xFFFF)), bf2f((unsigned short)(hv.x >> 16)),
                      bf2f((unsigned short)(hv.y & 0xFFFF)), bf2f((unsigned short)(hv.y >> 16)) };
      #pragma unroll
      for (int c = 0; c < 4; ++c) {
        acc[0][c] += w.x * hf[c];
        acc[1][c] += w.y * hf[c];
        acc[2][c] += w.z * hf[c];
        acc[3][c] += w.w * hf[c];
      }
    }
    #pragma unroll
    for (int k = 0; k < 4; ++k) {
      uint2 ov;
      float z0 = dd[k] * acc[k][0] + bb[0]; z0 = z0 > 0.f ? z0 : 0.f;
      float z1 = dd[k] * acc[k][1] + bb[1]; z1 = z1 > 0.f ? z1 : 0.f;
      float z2 = dd[k] * acc[k][2] + bb[2]; z2 = z2 > 0.f ? z2 : 0.f;
      float z3 = dd[k] * acc[k][3] + bb[3]; z3 = z3 > 0.f ? z3 : 0.f;
      ov.x = (unsigned)f2bf(z0) | ((unsigned)f2bf(z1) << 16);
      ov.y = (unsigned)f2bf(z2) | ((unsigned)f2bf(z3) << 16);
      *(uint2*)(Z1 + ((size_t)k * NN + n) * 256 + c0) = ov;
    }
  }
}

// ---------- fused layer-2 aggregation + colsum; k = blockIdx.y ----------
__global__ __launch_bounds__(256) void aggB_kernel(
    const unsigned short* __restrict__ Y2, const float* __restrict__ dinv,
    const int* __restrict__ rowstart, const int* __restrict__ csr_s,
    const float* __restrict__ w4s, const float* __restrict__ g2b,
    float* __restrict__ colsum)
{
  const int k = blockIdx.y;
  const int lane = threadIdx.x & 63;
  const int wv = threadIdx.x >> 6;
  const int gw = blockIdx.x * 4 + wv;
  const int nw = gridDim.x * 4;
  const int c0 = lane * 2;
  const float bb0 = g2b[c0], bb1 = g2b[c0 + 1];
  const unsigned short* Yk = Y2 + (size_t)k * NN * 128;
  const float* dk = dinv + (size_t)k * NN;
  float s0 = 0.f, s1 = 0.f;
  for (int n = gw; n < NN; n += nw) {
    float dd = dk[n];
    unsigned selfv = *(const unsigned*)(Yk + (size_t)n * 128 + c0);
    float a0 = dd * bf2f((unsigned short)(selfv & 0xFFFFu));
    float a1 = dd * bf2f((unsigned short)(selfv >> 16));
    int rs = rowstart[n], re = rowstart[n + 1];
    for (int p = rs; p < re; ++p) {
      int s = csr_s[p];
      float w = w4s[(size_t)p * 4 + k];
      unsigned hv = *(const unsigned*)(Yk + (size_t)s * 128 + c0);
      a0 += w * bf2f((unsigned short)(hv & 0xFFFFu));
      a1 += w * bf2f((unsigned short)(hv >> 16));
    }
    a0 = dd * a0 + bb0;
    a1 = dd * a1 + bb1;
    s0 += a0 > 0.f ? a0 : 0.f;
    s1 += a1 > 0.f ? a1 : 0.f;
  }
  __shared__ float lsum[128];
  if (threadIdx.x < 128) lsum[threadIdx.x] = 0.f;
  __syncthreads();
  atomicAdd(&lsum[c0], s0);
  atomicAdd(&lsum[c0 + 1], s1);
  __syncthreads();
  if (threadIdx.x < 128) atomicAdd(&colsum[k * 128 + threadIdx.x], lsum[threadIdx.x]);
}

// ---------- descriptors[k][o] = colsum_k/NN . fc_W + fc_b ----------
__global__ void desc_kernel(const float* __restrict__ colsum,
    const float* __restrict__ fcW, const float* __restrict__ fcb,
    float* __restrict__ out)
{
  int t = threadIdx.x;
  if (t >= 128) return;
  int k = t >> 5, o = t & 31;
  float acc = 0.f;
  for (int c = 0; c < 128; ++c)
    acc += colsum[k * 128 + c] * fcW[c * 32 + o];
  out[t] = acc * (1.f / (float)NN) + fcb[o];
}

extern "C" void kernel_launch(void* const* d_in, const int* in_sizes, int n_in,
                              void* d_out, int out_size, void* d_ws, size_t ws_size,
                              hipStream_t stream)
{
  (void)in_sizes; (void)n_in; (void)out_size; (void)ws_size;
  const float* X   = (const float*)d_in[0];
  const int*   ei  = (const int*)d_in[1];
  const float* Wh  = (const float*)d_in[2];
  const float* W1  = (const float*)d_in[3];
  const float* b1  = (const float*)d_in[4];
  const float* W2  = (const float*)d_in[5];
  const float* b2  = (const float*)d_in[6];
  const float* g1W = (const float*)d_in[7];
  const float* g1b = (const float*)d_in[8];
  const float* g2W = (const float*)d_in[9];
  const float* g2b = (const float*)d_in[10];
  const float* fcW = (const float*)d_in[11];
  const float* fcb = (const float*)d_in[12];
  float* out = (float*)d_out;

  char* ws = (char*)d_ws;
  size_t off = 0;
  auto alloc = [&](size_t bytes) -> void* {
    void* p = ws + off; off += (bytes + 255) & ~(size_t)255; return p;
  };
  unsigned short* WhT = (unsigned short*)alloc((size_t)128 * KPAD * 2);
  unsigned short* g1T = (unsigned short*)alloc((size_t)256 * 128 * 2);
  unsigned short* g2T = (unsigned short*)alloc((size_t)128 * 256 * 2);
  float* Wc  = (float*)alloc(2048 * 4);
  unsigned short* h0 = (unsigned short*)alloc((size_t)NN * 128 * 2);
  unsigned short* H1 = (unsigned short*)alloc((size_t)NN * 256 * 2);
  float* P   = (float*)alloc((size_t)NN * 16 * 4);
  float* deg = (float*)alloc((size_t)4 * NN * 4);
  float* dinv= (float*)alloc((size_t)4 * NN * 4);
  int* hist  = (int*)alloc((size_t)NN * 4);
  int* rowst = (int*)alloc((size_t)(NN + 1) * 4);
  int* cursor= (int*)alloc((size_t)NN * 4);
  int* bsum  = (int*)alloc(256 * 4);
  int* csr_s = (int*)alloc((size_t)NE * 4);
  int* csr_e = (int*)alloc((size_t)NE * 4);
  float4* Gk4 = (float4*)alloc((size_t)NE * 16);
  float4* w4  = (float4*)alloc((size_t)NE * 16);
  unsigned short* Z1 = (unsigned short*)alloc((size_t)4 * NN * 256 * 2);
  unsigned short* Y2 = (unsigned short*)alloc((size_t)4 * NN * 128 * 2);
  float* colsum = (float*)alloc(512 * 4);

  float* GkOut = out + 128;
  const int gEdge = (NE + 255) / 256;

  prep_kernel<<<(128*KPAD + 256*128 + 128*256 + 2048 + 255)/256, 256, 0, stream>>>(
      Wh, g1W, g2W, W1, WhT, g1T, g2T, Wc);
  init_kernel<<<(4*NN + 255)/256, 256, 0, stream>>>(deg, hist, colsum);
  gemm_kernel<1><<<dim3(391, 1), 256, 0, stream>>>(
      X, WhT, h0, NN, 128, INDIM, KPAD, KPAD / 64);
  gemm_kernel<0><<<dim3(391, 2), 256, 0, stream>>>(
      h0, g1T, H1, NN, 256, 128, 128, 2);
  p_kernel<<<196, 256, 0, stream>>>(h0, Wc, P);
  gk_kernel<<<gEdge, 256, 0, stream>>>(ei, P, b1, W2, b2, GkOut, Gk4, deg, hist);
  scan1_kernel<<<196, 256, 0, stream>>>(hist, rowst, bsum);
  scan2_kernel<<<1, 256, 0, stream>>>(bsum, 196);
  scan3_kernel<<<196, 256, 0, stream>>>(rowst, bsum, cursor);
  dinv_kernel<<<(4*NN + 255)/256, 256, 0, stream>>>(deg, dinv);
  csr_kernel<<<gEdge, 256, 0, stream>>>(ei, cursor, csr_s, csr_e);
  csrw_kernel<<<gEdge, 256, 0, stream>>>(csr_s, csr_e, Gk4, dinv, w4);
  aggA_kernel<<<2048, 256, 0, stream>>>(H1, Z1, dinv, rowst, csr_s, w4, g1b);
  gemm_kernel<0><<<dim3(1563, 1), 256, 0, stream>>>(
      Z1, g2T, Y2, 4 * NN, 128, 256, 256, 4);
  aggB_kernel<<<dim3(1024, 4), 256, 0, stream>>>(
      Y2, dinv, rowst, csr_s, (const float*)w4, g2b, colsum);
  desc_kernel<<<1, 128, 0, stream>>>(colsum, fcW, fcb, out);
}

// Round 10
// 891.540 us; speedup vs baseline: 1.4261x; 1.0581x over previous
//
#include <hip/hip_runtime.h>

#define NN 50000
#define NE 300000
#define INDIM 2000
#define KPAD 2048

typedef float f32x4 __attribute__((ext_vector_type(4)));
typedef __bf16 bf16x8 __attribute__((ext_vector_type(8)));
typedef unsigned short u16x8 __attribute__((ext_vector_type(8)));
typedef unsigned int u32;
typedef __attribute__((address_space(3))) u32 lds_u32;
typedef const __attribute__((address_space(1))) u32 glb_u32;

__device__ __forceinline__ unsigned short f2bf(float f) {
  return __builtin_bit_cast(unsigned short, (__bf16)f);   // v_cvt_pk_bf16_f32, RNE
}
__device__ __forceinline__ float bf2f(unsigned short h) {
  union { unsigned u; float f; } v; v.u = ((unsigned)h) << 16;
  return v.f;
}

// ---------- weight prep: transpose+bf16 weights, build per-node MLP matrix ----------
__global__ __launch_bounds__(256) void prep_kernel(
    const float* __restrict__ Wh, const float* __restrict__ g1,
    const float* __restrict__ g2, const float* __restrict__ W1,
    unsigned short* __restrict__ WhT, unsigned short* __restrict__ g1T,
    unsigned short* __restrict__ g2T, float* __restrict__ Wc)
{
  int i = blockIdx.x * 256 + threadIdx.x;
  if (i < 128 * KPAD) {                      // WhT[128][2048] (K zero-padded)
    int n = i >> 11, k = i & (KPAD - 1);
    WhT[i] = (k < INDIM) ? f2bf(Wh[(size_t)k * 128 + n]) : (unsigned short)0;
    return;
  }
  i -= 128 * KPAD;
  if (i < 256 * 128) {                       // g1T[256][128]
    int n = i >> 7, k = i & 127;
    g1T[i] = f2bf(g1[(size_t)k * 256 + n]);
    return;
  }
  i -= 256 * 128;
  if (i < 128 * 256) {                       // g2T[128][256]
    int n = i >> 8, k = i & 255;
    g2T[i] = f2bf(g2[(size_t)k * 128 + n]);
    return;
  }
  i -= 128 * 256;
  if (i < 2048) {                            // Wc[128][16]: cols 0-7 = W1[:128], 8-15 = W1[128:]
    int f = i >> 4, o = i & 15;
    int k = (o & 7) >> 1, h = o & 1;
    int fr = (o < 8) ? f : (128 + f);
    Wc[i] = W1[(size_t)k * 512 + fr * 2 + h];
  }
}

// ---------- bf16 MFMA GEMM, XOR-swizzled LDS, global_load_lds staging ----------
// LDS physical layout: LDS[r][s] = global[r][s ^ (r&7)] (16B slots); read XORs back.
template<int A_F32>
__global__ __launch_bounds__(256) void gemm_kernel(
    const void* __restrict__ Aptr, const unsigned short* __restrict__ BT,
    unsigned short* __restrict__ C, int M, int N, int Ka, int Kb, int nkb)
{
  __shared__ unsigned short Alds[128 * 64];
  __shared__ unsigned short Blds[128 * 64];
  const int tid = threadIdx.x, lane = tid & 63, wv = tid >> 6;
  const int mBase = blockIdx.x * 128, nBase = blockIdx.y * 128;
  const int wrow = (wv >> 1) * 64, wcol = (wv & 1) * 64;
  const int lr = lane >> 3, lk8 = (lane & 7) * 8;
  const int swzCol = (((lane & 7) ^ lr) << 3);   // pre-swizzled source col (shorts)
  const int stIdx = lr * 64 + swzCol;            // swizzled store slot (reg path)
  f32x4 acc[4][4] = {};

  for (int kb = 0; kb < nkb; ++kb) {
    int k0 = kb * 64;
    #pragma unroll
    for (int i = 0; i < 4; ++i) {            // stage B tile: linear dest, swizzled src
      int chunk = wv * 4 + i;
      int brow = nBase + chunk * 8 + lr;
      __builtin_amdgcn_global_load_lds(
          (glb_u32*)(BT + (size_t)brow * Kb + k0 + swzCol),
          (lds_u32*)&Blds[chunk * 512 + lane * 8], 16, 0, 0);
    }
    if (A_F32) {
      const float* Af = (const float*)Aptr;
      #pragma unroll
      for (int i = 0; i < 4; ++i) {          // reg-staged fp32->bf16
        int chunk = wv * 4 + i;
        int rg = mBase + chunk * 8 + lr; if (rg > M - 1) rg = M - 1;
        int kc = k0 + lk8; if (kc > Ka - 8) kc = Ka - 8;  // clamp; pad cols hit zero B
        const float4* s = (const float4*)(Af + (size_t)rg * Ka + kc);
        float4 f0 = s[0], f1 = s[1];
        u16x8 v;
        v[0]=f2bf(f0.x); v[1]=f2bf(f0.y); v[2]=f2bf(f0.z); v[3]=f2bf(f0.w);
        v[4]=f2bf(f1.x); v[5]=f2bf(f1.y); v[6]=f2bf(f1.z); v[7]=f2bf(f1.w);
        *(u16x8*)&Alds[chunk * 512 + stIdx] = v;
      }
    } else {
      const unsigned short* Ab = (const unsigned short*)Aptr;
      #pragma unroll
      for (int i = 0; i < 4; ++i) {
        int chunk = wv * 4 + i;
        int rg = mBase + chunk * 8 + lr; if (rg > M - 1) rg = M - 1;
        __builtin_amdgcn_global_load_lds(
            (glb_u32*)(Ab + (size_t)rg * Ka + k0 + swzCol),
            (lds_u32*)&Alds[chunk * 512 + lane * 8], 16, 0, 0);
      }
    }
    __syncthreads();
    #pragma unroll
    for (int kk = 0; kk < 2; ++kk) {
      const int r16 = lane & 15;
      const int slot = kk * 4 + (lane >> 4);          // 16B slot index 0..7
      bf16x8 a[4], b[4];
      #pragma unroll
      for (int mf = 0; mf < 4; ++mf) {
        int row = wrow + mf * 16 + r16;
        a[mf] = __builtin_bit_cast(bf16x8,
            *(const u16x8*)&Alds[row * 64 + ((slot ^ (row & 7)) << 3)]);
      }
      #pragma unroll
      for (int nf = 0; nf < 4; ++nf) {
        int row = wcol + nf * 16 + r16;
        b[nf] = __builtin_bit_cast(bf16x8,
            *(const u16x8*)&Blds[row * 64 + ((slot ^ (row & 7)) << 3)]);
      }
      #pragma unroll
      for (int mf = 0; mf < 4; ++mf)
        #pragma unroll
        for (int nf = 0; nf < 4; ++nf)
          acc[mf][nf] = __builtin_amdgcn_mfma_f32_16x16x32_bf16(a[mf], b[nf], acc[mf][nf], 0, 0, 0);
    }
    __syncthreads();
  }

  const int r16 = lane & 15, r4 = (lane >> 4) * 4;
  #pragma unroll
  for (int mf = 0; mf < 4; ++mf) {
    #pragma unroll
    for (int j = 0; j < 4; ++j) {
      int row = mBase + wrow + mf * 16 + r4 + j;
      if (row < M) {
        #pragma unroll
        for (int nf = 0; nf < 4; ++nf) {
          int col = nBase + wcol + nf * 16 + r16;
          C[(size_t)row * N + col] = f2bf(acc[mf][nf][j]);
        }
      }
    }
  }
}

// ---------- P[n][16] = h0[n] . Wc ----------
__global__ __launch_bounds__(256) void p_kernel(const unsigned short* __restrict__ h0,
    const float* __restrict__ Wc, float* __restrict__ P)
{
  __shared__ float wl[2048];
  for (int i = threadIdx.x; i < 2048; i += 256) wl[i] = Wc[i];
  __syncthreads();
  int n = blockIdx.x * 256 + threadIdx.x;
  if (n >= NN) return;
  const unsigned short* hr = h0 + (size_t)n * 128;
  float acc[16];
  #pragma unroll
  for (int o = 0; o < 16; ++o) acc[o] = 0.f;
  for (int f8 = 0; f8 < 128; f8 += 8) {
    u16x8 hv = *(const u16x8*)(hr + f8);
    #pragma unroll
    for (int j = 0; j < 8; ++j) {
      float v = bf2f(hv[j]);
      #pragma unroll
      for (int o = 0; o < 16; ++o) acc[o] += v * wl[(f8 + j) * 16 + o];
    }
  }
  #pragma unroll
  for (int o = 0; o < 16; ++o) P[(size_t)n * 16 + o] = acc[o];
}

__global__ __launch_bounds__(256) void init_kernel(float* deg, int* hist, float* colsum)
{
  int i = blockIdx.x * 256 + threadIdx.x;
  if (i < 4 * NN) deg[i] = 1.0f;           // self-loop weight; layout [n][4]
  if (i < NN) hist[i] = 0;
  if (i < 512) colsum[i] = 0.f;
}

// ---------- edge MLP: Gk + deg ([n][4] layout) + dst histogram ----------
__global__ __launch_bounds__(256) void gk_kernel(
    const int* __restrict__ ei, const float* __restrict__ P,
    const float* __restrict__ b1, const float* __restrict__ W2,
    const float* __restrict__ b2, float* __restrict__ GkOut,
    float4* __restrict__ Gk4, float* __restrict__ deg, int* __restrict__ hist)
{
  int e = blockIdx.x * 256 + threadIdx.x;
  if (e >= NE) return;
  int s = ei[e], d = ei[NE + e];
  const float4* Ps = (const float4*)(P + (size_t)s * 16);
  const float4* Pd = (const float4*)(P + (size_t)d * 16);
  float4 p1a = Ps[0], p1b = Ps[1];
  float4 p2a = Pd[2], p2b = Pd[3];
  float p1[8] = {p1a.x, p1a.y, p1a.z, p1a.w, p1b.x, p1b.y, p1b.z, p1b.w};
  float p2[8] = {p2a.x, p2a.y, p2a.z, p2a.w, p2b.x, p2b.y, p2b.z, p2b.w};
  float g[4];
  #pragma unroll
  for (int k = 0; k < 4; ++k) {
    float h0v = p1[2*k]   + p2[2*k]   + b1[2*k];
    float h1v = p1[2*k+1] + p2[2*k+1] + b1[2*k+1];
    h0v = h0v > 0.f ? h0v : 0.f;
    h1v = h1v > 0.f ? h1v : 0.f;
    float pre = h0v * W2[2*k] + h1v * W2[2*k+1] + b2[k];
    g[k] = 1.f / (1.f + expf(-pre));
    GkOut[(size_t)k * NE + e] = g[k];
    atomicAdd(&deg[(size_t)d * 4 + k], g[k]);
  }
  Gk4[e] = make_float4(g[0], g[1], g[2], g[3]);
  atomicAdd(&hist[d], 1);
}

// ---------- 3-phase exclusive scan over hist[50000] ----------
__global__ __launch_bounds__(256) void scan1_kernel(const int* __restrict__ hist,
    int* __restrict__ excl, int* __restrict__ bsum)
{
  __shared__ int sm[256];
  int t = threadIdx.x, i = blockIdx.x * 256 + t;
  int v = (i < NN) ? hist[i] : 0;
  sm[t] = v;
  __syncthreads();
  for (int off = 1; off < 256; off <<= 1) {
    int y = (t >= off) ? sm[t - off] : 0;
    __syncthreads();
    sm[t] += y;
    __syncthreads();
  }
  if (i < NN) excl[i] = sm[t] - v;
  if (t == 255) bsum[blockIdx.x] = sm[255];
}

__global__ __launch_bounds__(256) void scan2_kernel(int* bsum, int nb)
{
  __shared__ int sm[256];
  int t = threadIdx.x;
  int v = (t < nb) ? bsum[t] : 0;
  sm[t] = v;
  __syncthreads();
  for (int off = 1; off < 256; off <<= 1) {
    int y = (t >= off) ? sm[t - off] : 0;
    __syncthreads();
    sm[t] += y;
    __syncthreads();
  }
  if (t < nb) bsum[t] = sm[t] - v;
}

__global__ __launch_bounds__(256) void scan3_kernel(int* __restrict__ rowstart,
    const int* __restrict__ bsum, int* __restrict__ cursor)
{
  int i = blockIdx.x * 256 + threadIdx.x;
  if (i < NN) {
    int v = rowstart[i] + bsum[blockIdx.x];
    rowstart[i] = v;
    cursor[i] = v;
  }
  if (i == 0) rowstart[NN] = NE;
}

__global__ __launch_bounds__(256) void dinv_kernel(const float* __restrict__ deg,
    float* __restrict__ dinv)
{
  int i = blockIdx.x * 256 + threadIdx.x;
  if (i < 4 * NN) dinv[i] = rsqrtf(deg[i]);
}

// ---------- CSR scatter (counting sort by dst) ----------
__global__ __launch_bounds__(256) void csr_kernel(const int* __restrict__ ei,
    int* __restrict__ cursor, int* __restrict__ csr_s, int* __restrict__ csr_e)
{
  int e = blockIdx.x * 256 + threadIdx.x;
  if (e >= NE) return;
  int s = ei[e], d = ei[NE + e];
  int pos = atomicAdd(&cursor[d], 1);
  csr_s[pos] = s;
  csr_e[pos] = e;
}

// ---------- per-slot weights for all 4 k: w4[p] = Gk[e] * dinv4[src] ----------
__global__ __launch_bounds__(256) void csrw_kernel(const int* __restrict__ csr_s,
    const int* __restrict__ csr_e, const float4* __restrict__ Gk4,
    const float4* __restrict__ dinv4, float4* __restrict__ w4)
{
  int p = blockIdx.x * 256 + threadIdx.x;
  if (p >= NE) return;
  int s = csr_s[p], e = csr_e[p];
  float4 g = Gk4[e];
  float4 dv = dinv4[s];
  float4 w;
  w.x = g.x * dv.x;
  w.y = g.y * dv.y;
  w.z = g.z * dv.z;
  w.w = g.w * dv.w;
  w4[p] = w;
}

// ---------- fused 4-k layer-1 aggregation: H1[NN,256] -> Z1[n][4][256] (+b,relu) ----------
__global__ __launch_bounds__(256) void aggA_kernel(
    const unsigned short* __restrict__ H1, unsigned short* __restrict__ Z1,
    const float4* __restrict__ dinv4, const int* __restrict__ rowstart,
    const int* __restrict__ csr_s, const float4* __restrict__ w4,
    const float* __restrict__ g1b)
{
  const int lane = threadIdx.x & 63;
  const int wv = threadIdx.x >> 6;
  const int gw = blockIdx.x * 4 + wv;
  const int nw = gridDim.x * 4;
  const int c0 = lane * 4;
  float bb[4];
  #pragma unroll
  for (int c = 0; c < 4; ++c) bb[c] = g1b[c0 + c];
  for (int n = gw; n < NN; n += nw) {
    float4 dv = dinv4[n];
    float dd[4] = { dv.x, dv.y, dv.z, dv.w };
    uint2 sv = *(const uint2*)(H1 + (size_t)n * 256 + c0);
    float sf[4] = { bf2f((unsigned short)(sv.x & 0xFFFF)), bf2f((unsigned short)(sv.x >> 16)),
                    bf2f((unsigned short)(sv.y & 0xFFFF)), bf2f((unsigned short)(sv.y >> 16)) };
    float acc[4][4];
    #pragma unroll
    for (int k = 0; k < 4; ++k)
      #pragma unroll
      for (int c = 0; c < 4; ++c) acc[k][c] = dd[k] * sf[c];
    int rs = rowstart[n], re = rowstart[n + 1];
    for (int p = rs; p < re; ++p) {
      int s = csr_s[p];
      float4 w = w4[p];
      uint2 hv = *(const uint2*)(H1 + (size_t)s * 256 + c0);
      float hf[4] = { bf2f((unsigned short)(hv.x & 0xFFFF)), bf2f((unsigned short)(hv.x >> 16)),
                      bf2f((unsigned short)(hv.y & 0xFFFF)), bf2f((unsigned short)(hv.y >> 16)) };
      #pragma unroll
      for (int c = 0; c < 4; ++c) {
        acc[0][c] += w.x * hf[c];
        acc[1][c] += w.y * hf[c];
        acc[2][c] += w.z * hf[c];
        acc[3][c] += w.w * hf[c];
      }
    }
    #pragma unroll
    for (int k = 0; k < 4; ++k) {
      uint2 ov;
      float z0 = dd[k] * acc[k][0] + bb[0]; z0 = z0 > 0.f ? z0 : 0.f;
      float z1 = dd[k] * acc[k][1] + bb[1]; z1 = z1 > 0.f ? z1 : 0.f;
      float z2 = dd[k] * acc[k][2] + bb[2]; z2 = z2 > 0.f ? z2 : 0.f;
      float z3 = dd[k] * acc[k][3] + bb[3]; z3 = z3 > 0.f ? z3 : 0.f;
      ov.x = (unsigned)f2bf(z0) | ((unsigned)f2bf(z1) << 16);
      ov.y = (unsigned)f2bf(z2) | ((unsigned)f2bf(z3) << 16);
      *(uint2*)(Z1 + ((size_t)n * 4 + k) * 256 + c0) = ov;   // interleaved [n][4][256]
    }
  }
}

// ---------- single-pass layer-2 aggregation + colsum over Y2[n][4][128] ----------
__global__ __launch_bounds__(256) void aggB_kernel(
    const unsigned short* __restrict__ Y2, const float4* __restrict__ dinv4,
    const int* __restrict__ rowstart, const int* __restrict__ csr_s,
    const float4* __restrict__ w4, const float* __restrict__ g2b,
    float* __restrict__ colsum)
{
  const int lane = threadIdx.x & 63;
  const int wv = threadIdx.x >> 6;
  const int gw = blockIdx.x * 4 + wv;
  const int nw = gridDim.x * 4;
  const int kk = lane >> 4;                 // this lane's k
  const int c0 = (lane & 15) * 8;           // this lane's 8 columns
  float bb[8];
  #pragma unroll
  for (int j = 0; j < 8; ++j) bb[j] = g2b[c0 + j];
  float s[8] = {};
  for (int n = gw; n < NN; n += nw) {
    float4 dv = dinv4[n];
    float dd = kk == 0 ? dv.x : kk == 1 ? dv.y : kk == 2 ? dv.z : dv.w;
    u16x8 sv = *(const u16x8*)(Y2 + (size_t)n * 512 + lane * 8);   // 1KB/row, all 4 k
    float a[8];
    #pragma unroll
    for (int j = 0; j < 8; ++j) a[j] = dd * bf2f(sv[j]);
    int rs = rowstart[n], re = rowstart[n + 1];
    for (int p = rs; p < re; ++p) {
      int src = csr_s[p];
      float4 w4v = w4[p];
      float w = kk == 0 ? w4v.x : kk == 1 ? w4v.y : kk == 2 ? w4v.z : w4v.w;
      u16x8 hv = *(const u16x8*)(Y2 + (size_t)src * 512 + lane * 8);
      #pragma unroll
      for (int j = 0; j < 8; ++j) a[j] += w * bf2f(hv[j]);
    }
    #pragma unroll
    for (int j = 0; j < 8; ++j) {
      float z = dd * a[j] + bb[j];
      s[j] += z > 0.f ? z : 0.f;
    }
  }
  __shared__ float lsum[4 * 512];
  #pragma unroll
  for (int j = 0; j < 8; ++j) lsum[wv * 512 + kk * 128 + c0 + j] = s[j];
  __syncthreads();
  for (int i = threadIdx.x; i < 512; i += 256)
    atomicAdd(&colsum[i], lsum[i] + lsum[512 + i] + lsum[1024 + i] + lsum[1536 + i]);
}

// ---------- descriptors[k][o] = colsum_k/NN . fc_W + fc_b ----------
__global__ void desc_kernel(const float* __restrict__ colsum,
    const float* __restrict__ fcW, const float* __restrict__ fcb,
    float* __restrict__ out)
{
  int t = threadIdx.x;
  if (t >= 128) return;
  int k = t >> 5, o = t & 31;
  float acc = 0.f;
  for (int c = 0; c < 128; ++c)
    acc += colsum[k * 128 + c] * fcW[c * 32 + o];
  out[t] = acc * (1.f / (float)NN) + fcb[o];
}

extern "C" void kernel_launch(void* const* d_in, const int* in_sizes, int n_in,
                              void* d_out, int out_size, void* d_ws, size_t ws_size,
                              hipStream_t stream)
{
  (void)in_sizes; (void)n_in; (void)out_size; (void)ws_size;
  const float* X   = (const float*)d_in[0];
  const int*   ei  = (const int*)d_in[1];
  const float* Wh  = (const float*)d_in[2];
  const float* W1  = (const float*)d_in[3];
  const float* b1  = (const float*)d_in[4];
  const float* W2  = (const float*)d_in[5];
  const float* b2  = (const float*)d_in[6];
  const float* g1W = (const float*)d_in[7];
  const float* g1b = (const float*)d_in[8];
  const float* g2W = (const float*)d_in[9];
  const float* g2b = (const float*)d_in[10];
  const float* fcW = (const float*)d_in[11];
  const float* fcb = (const float*)d_in[12];
  float* out = (float*)d_out;

  char* ws = (char*)d_ws;
  size_t off = 0;
  auto alloc = [&](size_t bytes) -> void* {
    void* p = ws + off; off += (bytes + 255) & ~(size_t)255; return p;
  };
  unsigned short* WhT = (unsigned short*)alloc((size_t)128 * KPAD * 2);
  unsigned short* g1T = (unsigned short*)alloc((size_t)256 * 128 * 2);
  unsigned short* g2T = (unsigned short*)alloc((size_t)128 * 256 * 2);
  float* Wc  = (float*)alloc(2048 * 4);
  unsigned short* h0 = (unsigned short*)alloc((size_t)NN * 128 * 2);
  unsigned short* H1 = (unsigned short*)alloc((size_t)NN * 256 * 2);
  float* P   = (float*)alloc((size_t)NN * 16 * 4);
  float* deg = (float*)alloc((size_t)4 * NN * 4);     // [n][4]
  float* dinv= (float*)alloc((size_t)4 * NN * 4);     // [n][4]
  int* hist  = (int*)alloc((size_t)NN * 4);
  int* rowst = (int*)alloc((size_t)(NN + 1) * 4);
  int* cursor= (int*)alloc((size_t)NN * 4);
  int* bsum  = (int*)alloc(256 * 4);
  int* csr_s = (int*)alloc((size_t)NE * 4);
  int* csr_e = (int*)alloc((size_t)NE * 4);
  float4* Gk4 = (float4*)alloc((size_t)NE * 16);
  float4* w4  = (float4*)alloc((size_t)NE * 16);
  unsigned short* Z1 = (unsigned short*)alloc((size_t)4 * NN * 256 * 2);  // [n][4][256]
  unsigned short* Y2 = (unsigned short*)alloc((size_t)4 * NN * 128 * 2);  // [n][4][128]
  float* colsum = (float*)alloc(512 * 4);

  float* GkOut = out + 128;
  const int gEdge = (NE + 255) / 256;

  prep_kernel<<<(128*KPAD + 256*128 + 128*256 + 2048 + 255)/256, 256, 0, stream>>>(
      Wh, g1W, g2W, W1, WhT, g1T, g2T, Wc);
  init_kernel<<<(4*NN + 255)/256, 256, 0, stream>>>(deg, hist, colsum);
  gemm_kernel<1><<<dim3(391, 1), 256, 0, stream>>>(
      X, WhT, h0, NN, 128, INDIM, KPAD, KPAD / 64);
  gemm_kernel<0><<<dim3(391, 2), 256, 0, stream>>>(
      h0, g1T, H1, NN, 256, 128, 128, 2);
  p_kernel<<<196, 256, 0, stream>>>(h0, Wc, P);
  gk_kernel<<<gEdge, 256, 0, stream>>>(ei, P, b1, W2, b2, GkOut, Gk4, deg, hist);
  scan1_kernel<<<196, 256, 0, stream>>>(hist, rowst, bsum);
  scan2_kernel<<<1, 256, 0, stream>>>(bsum, 196);
  scan3_kernel<<<196, 256, 0, stream>>>(rowst, bsum, cursor);
  dinv_kernel<<<(4*NN + 255)/256, 256, 0, stream>>>(deg, dinv);
  csr_kernel<<<gEdge, 256, 0, stream>>>(ei, cursor, csr_s, csr_e);
  csrw_kernel<<<gEdge, 256, 0, stream>>>(csr_s, csr_e, Gk4, (const float4*)dinv, w4);
  aggA_kernel<<<2048, 256, 0, stream>>>(H1, Z1, (const float4*)dinv, rowst, csr_s, w4, g1b);
  gemm_kernel<0><<<dim3(1563, 1), 256, 0, stream>>>(
      Z1, g2T, Y2, 4 * NN, 128, 256, 256, 4);
  aggB_kernel<<<2048, 256, 0, stream>>>(
      Y2, (const float4*)dinv, rowst, csr_s, w4, g2b, colsum);
  desc_kernel<<<1, 128, 0, stream>>>(colsum, fcW, fcb, out);
}

// Round 11
// 873.385 us; speedup vs baseline: 1.4557x; 1.0208x over previous
//
#include <hip/hip_runtime.h>

#define NN 50000
#define NE 300000
#define INDIM 2000
#define KPAD 2048

typedef float f32x4 __attribute__((ext_vector_type(4)));
typedef __bf16 bf16x8 __attribute__((ext_vector_type(8)));
typedef unsigned short u16x8 __attribute__((ext_vector_type(8)));
typedef unsigned int u32;
typedef __attribute__((address_space(3))) u32 lds_u32;
typedef const __attribute__((address_space(1))) u32 glb_u32;

__device__ __forceinline__ unsigned short f2bf(float f) {
  return __builtin_bit_cast(unsigned short, (__bf16)f);   // v_cvt_pk_bf16_f32, RNE
}
__device__ __forceinline__ float bf2f(unsigned short h) {
  union { unsigned u; float f; } v; v.u = ((unsigned)h) << 16;
  return v.f;
}

// ---------- weight prep + scratch init (fused) ----------
__global__ __launch_bounds__(256) void prep_kernel(
    const float* __restrict__ Wh, const float* __restrict__ g1,
    const float* __restrict__ g2, const float* __restrict__ W1,
    unsigned short* __restrict__ WhT, unsigned short* __restrict__ g1T,
    unsigned short* __restrict__ g2T, float* __restrict__ Wc,
    float* __restrict__ deg, int* __restrict__ hist, float* __restrict__ colsum)
{
  int i = blockIdx.x * 256 + threadIdx.x;
  if (i < 128 * KPAD) {                      // WhT[128][2048] (K zero-padded)
    int n = i >> 11, k = i & (KPAD - 1);
    WhT[i] = (k < INDIM) ? f2bf(Wh[(size_t)k * 128 + n]) : (unsigned short)0;
    return;
  }
  i -= 128 * KPAD;
  if (i < 256 * 128) {                       // g1T[256][128]
    int n = i >> 7, k = i & 127;
    g1T[i] = f2bf(g1[(size_t)k * 256 + n]);
    return;
  }
  i -= 256 * 128;
  if (i < 128 * 256) {                       // g2T[128][256]
    int n = i >> 8, k = i & 255;
    g2T[i] = f2bf(g2[(size_t)k * 128 + n]);
    return;
  }
  i -= 128 * 256;
  if (i < 2048) {                            // Wc[128][16]: cols 0-7 = W1[:128], 8-15 = W1[128:]
    int f = i >> 4, o = i & 15;
    int k = (o & 7) >> 1, h = o & 1;
    int fr = (o < 8) ? f : (128 + f);
    Wc[i] = W1[(size_t)k * 512 + fr * 2 + h];
    return;
  }
  i -= 2048;
  if (i < 4 * NN) {                          // scratch init
    deg[i] = 1.0f;                           // self-loop weight; layout [n][4]
    if (i < NN) hist[i] = 0;
    if (i < 512) colsum[i] = 0.f;
  }
}

// ---------- bf16 MFMA GEMM, XOR-swizzled LDS, global_load_lds staging ----------
// LDS physical layout: LDS[r][s] = global[r][s ^ (r&7)] (16B slots); read XORs back.
template<int A_F32>
__global__ __launch_bounds__(256) void gemm_kernel(
    const void* __restrict__ Aptr, const unsigned short* __restrict__ BT,
    unsigned short* __restrict__ C, int M, int N, int Ka, int Kb, int nkb)
{
  __shared__ unsigned short Alds[128 * 64];
  __shared__ unsigned short Blds[128 * 64];
  const int tid = threadIdx.x, lane = tid & 63, wv = tid >> 6;
  const int mBase = blockIdx.x * 128, nBase = blockIdx.y * 128;
  const int wrow = (wv >> 1) * 64, wcol = (wv & 1) * 64;
  const int lr = lane >> 3, lk8 = (lane & 7) * 8;
  const int swzCol = (((lane & 7) ^ lr) << 3);   // pre-swizzled source col (shorts)
  const int stIdx = lr * 64 + swzCol;            // swizzled store slot (reg path)
  f32x4 acc[4][4] = {};

  for (int kb = 0; kb < nkb; ++kb) {
    int k0 = kb * 64;
    #pragma unroll
    for (int i = 0; i < 4; ++i) {            // stage B tile: linear dest, swizzled src
      int chunk = wv * 4 + i;
      int brow = nBase + chunk * 8 + lr;
      __builtin_amdgcn_global_load_lds(
          (glb_u32*)(BT + (size_t)brow * Kb + k0 + swzCol),
          (lds_u32*)&Blds[chunk * 512 + lane * 8], 16, 0, 0);
    }
    if (A_F32) {
      const float* Af = (const float*)Aptr;
      #pragma unroll
      for (int i = 0; i < 4; ++i) {          // reg-staged fp32->bf16
        int chunk = wv * 4 + i;
        int rg = mBase + chunk * 8 + lr; if (rg > M - 1) rg = M - 1;
        int kc = k0 + lk8; if (kc > Ka - 8) kc = Ka - 8;  // clamp; pad cols hit zero B
        const float4* s = (const float4*)(Af + (size_t)rg * Ka + kc);
        float4 f0 = s[0], f1 = s[1];
        u16x8 v;
        v[0]=f2bf(f0.x); v[1]=f2bf(f0.y); v[2]=f2bf(f0.z); v[3]=f2bf(f0.w);
        v[4]=f2bf(f1.x); v[5]=f2bf(f1.y); v[6]=f2bf(f1.z); v[7]=f2bf(f1.w);
        *(u16x8*)&Alds[chunk * 512 + stIdx] = v;
      }
    } else {
      const unsigned short* Ab = (const unsigned short*)Aptr;
      #pragma unroll
      for (int i = 0; i < 4; ++i) {
        int chunk = wv * 4 + i;
        int rg = mBase + chunk * 8 + lr; if (rg > M - 1) rg = M - 1;
        __builtin_amdgcn_global_load_lds(
            (glb_u32*)(Ab + (size_t)rg * Ka + k0 + swzCol),
            (lds_u32*)&Alds[chunk * 512 + lane * 8], 16, 0, 0);
      }
    }
    __syncthreads();
    #pragma unroll
    for (int kk = 0; kk < 2; ++kk) {
      const int r16 = lane & 15;
      const int slot = kk * 4 + (lane >> 4);          // 16B slot index 0..7
      bf16x8 a[4], b[4];
      #pragma unroll
      for (int mf = 0; mf < 4; ++mf) {
        int row = wrow + mf * 16 + r16;
        a[mf] = __builtin_bit_cast(bf16x8,
            *(const u16x8*)&Alds[row * 64 + ((slot ^ (row & 7)) << 3)]);
      }
      #pragma unroll
      for (int nf = 0; nf < 4; ++nf) {
        int row = wcol + nf * 16 + r16;
        b[nf] = __builtin_bit_cast(bf16x8,
            *(const u16x8*)&Blds[row * 64 + ((slot ^ (row & 7)) << 3)]);
      }
      #pragma unroll
      for (int mf = 0; mf < 4; ++mf)
        #pragma unroll
        for (int nf = 0; nf < 4; ++nf)
          acc[mf][nf] = __builtin_amdgcn_mfma_f32_16x16x32_bf16(a[mf], b[nf], acc[mf][nf], 0, 0, 0);
    }
    __syncthreads();
  }

  const int r16 = lane & 15, r4 = (lane >> 4) * 4;
  #pragma unroll
  for (int mf = 0; mf < 4; ++mf) {
    #pragma unroll
    for (int j = 0; j < 4; ++j) {
      int row = mBase + wrow + mf * 16 + r4 + j;
      if (row < M) {
        #pragma unroll
        for (int nf = 0; nf < 4; ++nf) {
          int col = nBase + wcol + nf * 16 + r16;
          C[(size_t)row * N + col] = f2bf(acc[mf][nf][j]);
        }
      }
    }
  }
}

// ---------- P[n][16] = h0[n] . Wc ----------
__global__ __launch_bounds__(256) void p_kernel(const unsigned short* __restrict__ h0,
    const float* __restrict__ Wc, float* __restrict__ P)
{
  __shared__ float wl[2048];
  for (int i = threadIdx.x; i < 2048; i += 256) wl[i] = Wc[i];
  __syncthreads();
  int n = blockIdx.x * 256 + threadIdx.x;
  if (n >= NN) return;
  const unsigned short* hr = h0 + (size_t)n * 128;
  float acc[16];
  #pragma unroll
  for (int o = 0; o < 16; ++o) acc[o] = 0.f;
  for (int f8 = 0; f8 < 128; f8 += 8) {
    u16x8 hv = *(const u16x8*)(hr + f8);
    #pragma unroll
    for (int j = 0; j < 8; ++j) {
      float v = bf2f(hv[j]);
      #pragma unroll
      for (int o = 0; o < 16; ++o) acc[o] += v * wl[(f8 + j) * 16 + o];
    }
  }
  #pragma unroll
  for (int o = 0; o < 16; ++o) P[(size_t)n * 16 + o] = acc[o];
}

// ---------- edge MLP: Gk + deg ([n][4] layout) + dst histogram ----------
__global__ __launch_bounds__(256) void gk_kernel(
    const int* __restrict__ ei, const float* __restrict__ P,
    const float* __restrict__ b1, const float* __restrict__ W2,
    const float* __restrict__ b2, float* __restrict__ GkOut,
    float4* __restrict__ Gk4, float* __restrict__ deg, int* __restrict__ hist)
{
  int e = blockIdx.x * 256 + threadIdx.x;
  if (e >= NE) return;
  int s = ei[e], d = ei[NE + e];
  const float4* Ps = (const float4*)(P + (size_t)s * 16);
  const float4* Pd = (const float4*)(P + (size_t)d * 16);
  float4 p1a = Ps[0], p1b = Ps[1];
  float4 p2a = Pd[2], p2b = Pd[3];
  float p1[8] = {p1a.x, p1a.y, p1a.z, p1a.w, p1b.x, p1b.y, p1b.z, p1b.w};
  float p2[8] = {p2a.x, p2a.y, p2a.z, p2a.w, p2b.x, p2b.y, p2b.z, p2b.w};
  float g[4];
  #pragma unroll
  for (int k = 0; k < 4; ++k) {
    float h0v = p1[2*k]   + p2[2*k]   + b1[2*k];
    float h1v = p1[2*k+1] + p2[2*k+1] + b1[2*k+1];
    h0v = h0v > 0.f ? h0v : 0.f;
    h1v = h1v > 0.f ? h1v : 0.f;
    float pre = h0v * W2[2*k] + h1v * W2[2*k+1] + b2[k];
    g[k] = 1.f / (1.f + expf(-pre));
    GkOut[(size_t)k * NE + e] = g[k];
    atomicAdd(&deg[(size_t)d * 4 + k], g[k]);
  }
  Gk4[e] = make_float4(g[0], g[1], g[2], g[3]);
  atomicAdd(&hist[d], 1);
}

// ---------- 3-phase exclusive scan over hist[50000] ----------
__global__ __launch_bounds__(256) void scan1_kernel(const int* __restrict__ hist,
    int* __restrict__ excl, int* __restrict__ bsum)
{
  __shared__ int sm[256];
  int t = threadIdx.x, i = blockIdx.x * 256 + t;
  int v = (i < NN) ? hist[i] : 0;
  sm[t] = v;
  __syncthreads();
  for (int off = 1; off < 256; off <<= 1) {
    int y = (t >= off) ? sm[t - off] : 0;
    __syncthreads();
    sm[t] += y;
    __syncthreads();
  }
  if (i < NN) excl[i] = sm[t] - v;
  if (t == 255) bsum[blockIdx.x] = sm[255];
}

__global__ __launch_bounds__(256) void scan2_kernel(int* bsum, int nb)
{
  __shared__ int sm[256];
  int t = threadIdx.x;
  int v = (t < nb) ? bsum[t] : 0;
  sm[t] = v;
  __syncthreads();
  for (int off = 1; off < 256; off <<= 1) {
    int y = (t >= off) ? sm[t - off] : 0;
    __syncthreads();
    sm[t] += y;
    __syncthreads();
  }
  if (t < nb) bsum[t] = sm[t] - v;
}

// ---------- scan finalize + cursor + dinv (fused; deg is final after gk) ----------
__global__ __launch_bounds__(256) void scan3_kernel(int* __restrict__ rowstart,
    const int* __restrict__ bsum, int* __restrict__ cursor,
    const float4* __restrict__ deg4, float4* __restrict__ dinv4)
{
  int i = blockIdx.x * 256 + threadIdx.x;
  if (i < NN) {
    int v = rowstart[i] + bsum[blockIdx.x];
    rowstart[i] = v;
    cursor[i] = v;
    float4 dg = deg4[i];
    float4 dv;
    dv.x = rsqrtf(dg.x); dv.y = rsqrtf(dg.y);
    dv.z = rsqrtf(dg.z); dv.w = rsqrtf(dg.w);
    dinv4[i] = dv;
  }
  if (i == 0) rowstart[NN] = NE;
}

// ---------- CSR scatter + per-slot weights (fused counting sort by dst) ----------
__global__ __launch_bounds__(256) void csr_kernel(const int* __restrict__ ei,
    int* __restrict__ cursor, const float4* __restrict__ Gk4,
    const float4* __restrict__ dinv4, int* __restrict__ csr_s,
    float4* __restrict__ w4)
{
  int e = blockIdx.x * 256 + threadIdx.x;
  if (e >= NE) return;
  int s = ei[e], d = ei[NE + e];
  int pos = atomicAdd(&cursor[d], 1);
  csr_s[pos] = s;
  float4 g = Gk4[e];
  float4 dv = dinv4[s];
  float4 w;
  w.x = g.x * dv.x;
  w.y = g.y * dv.y;
  w.z = g.z * dv.z;
  w.w = g.w * dv.w;
  w4[pos] = w;
}

// ---------- fused 4-k layer-1 aggregation: H1[NN,256] -> Z1[n][4][256] (+b,relu) ----------
// edge loop software-pipelined: next edge's {index, weight, gather} issued before current FMAs
__global__ __launch_bounds__(256) void aggA_kernel(
    const unsigned short* __restrict__ H1, unsigned short* __restrict__ Z1,
    const float4* __restrict__ dinv4, const int* __restrict__ rowstart,
    const int* __restrict__ csr_s, const float4* __restrict__ w4,
    const float* __restrict__ g1b)
{
  const int lane = threadIdx.x & 63;
  const int wv = threadIdx.x >> 6;
  const int gw = blockIdx.x * 4 + wv;
  const int nw = gridDim.x * 4;
  const int c0 = lane * 4;
  float bb[4];
  #pragma unroll
  for (int c = 0; c < 4; ++c) bb[c] = g1b[c0 + c];
  for (int n = gw; n < NN; n += nw) {
    float4 dv = dinv4[n];
    float dd[4] = { dv.x, dv.y, dv.z, dv.w };
    uint2 sv = *(const uint2*)(H1 + (size_t)n * 256 + c0);
    float sf[4] = { bf2f((unsigned short)(sv.x & 0xFFFF)), bf2f((unsigned short)(sv.x >> 16)),
                    bf2f((unsigned short)(sv.y & 0xFFFF)), bf2f((unsigned short)(sv.y >> 16)) };
    float acc[4][4];
    #pragma unroll
    for (int k = 0; k < 4; ++k)
      #pragma unroll
      for (int c = 0; c < 4; ++c) acc[k][c] = dd[k] * sf[c];
    int rs = rowstart[n], re = rowstart[n + 1];
    if (rs < re) {
      int sC = csr_s[rs];
      float4 wC = w4[rs];
      uint2 hC = *(const uint2*)(H1 + (size_t)sC * 256 + c0);
      for (int p = rs + 1; p < re; ++p) {
        int sNx = csr_s[p];
        float4 wN = w4[p];
        uint2 hN = *(const uint2*)(H1 + (size_t)sNx * 256 + c0);
        float hf[4] = { bf2f((unsigned short)(hC.x & 0xFFFF)), bf2f((unsigned short)(hC.x >> 16)),
                        bf2f((unsigned short)(hC.y & 0xFFFF)), bf2f((unsigned short)(hC.y >> 16)) };
        #pragma unroll
        for (int c = 0; c < 4; ++c) {
          acc[0][c] += wC.x * hf[c];
          acc[1][c] += wC.y * hf[c];
          acc[2][c] += wC.z * hf[c];
          acc[3][c] += wC.w * hf[c];
        }
        wC = wN; hC = hN;
      }
      float hf[4] = { bf2f((unsigned short)(hC.x & 0xFFFF)), bf2f((unsigned short)(hC.x >> 16)),
                      bf2f((unsigned short)(hC.y & 0xFFFF)), bf2f((unsigned short)(hC.y >> 16)) };
      #pragma unroll
      for (int c = 0; c < 4; ++c) {
        acc[0][c] += wC.x * hf[c];
        acc[1][c] += wC.y * hf[c];
        acc[2][c] += wC.z * hf[c];
        acc[3][c] += wC.w * hf[c];
      }
    }
    #pragma unroll
    for (int k = 0; k < 4; ++k) {
      uint2 ov;
      float z0 = dd[k] * acc[k][0] + bb[0]; z0 = z0 > 0.f ? z0 : 0.f;
      float z1 = dd[k] * acc[k][1] + bb[1]; z1 = z1 > 0.f ? z1 : 0.f;
      float z2 = dd[k] * acc[k][2] + bb[2]; z2 = z2 > 0.f ? z2 : 0.f;
      float z3 = dd[k] * acc[k][3] + bb[3]; z3 = z3 > 0.f ? z3 : 0.f;
      ov.x = (unsigned)f2bf(z0) | ((unsigned)f2bf(z1) << 16);
      ov.y = (unsigned)f2bf(z2) | ((unsigned)f2bf(z3) << 16);
      *(uint2*)(Z1 + ((size_t)n * 4 + k) * 256 + c0) = ov;   // interleaved [n][4][256]
    }
  }
}

// ---------- single-pass layer-2 aggregation + colsum over Y2[n][4][128] ----------
// same software-pipelined edge loop
__global__ __launch_bounds__(256) void aggB_kernel(
    const unsigned short* __restrict__ Y2, const float4* __restrict__ dinv4,
    const int* __restrict__ rowstart, const int* __restrict__ csr_s,
    const float4* __restrict__ w4, const float* __restrict__ g2b,
    float* __restrict__ colsum)
{
  const int lane = threadIdx.x & 63;
  const int wv = threadIdx.x >> 6;
  const int gw = blockIdx.x * 4 + wv;
  const int nw = gridDim.x * 4;
  const int kk = lane >> 4;                 // this lane's k
  const int c0 = (lane & 15) * 8;           // this lane's 8 columns
  float bb[8];
  #pragma unroll
  for (int j = 0; j < 8; ++j) bb[j] = g2b[c0 + j];
  float s[8] = {};
  for (int n = gw; n < NN; n += nw) {
    float4 dv = dinv4[n];
    float dd = kk == 0 ? dv.x : kk == 1 ? dv.y : kk == 2 ? dv.z : dv.w;
    u16x8 sv = *(const u16x8*)(Y2 + (size_t)n * 512 + lane * 8);   // 1KB/row, all 4 k
    float a[8];
    #pragma unroll
    for (int j = 0; j < 8; ++j) a[j] = dd * bf2f(sv[j]);
    int rs = rowstart[n], re = rowstart[n + 1];
    if (rs < re) {
      int sC = csr_s[rs];
      float4 wC4 = w4[rs];
      u16x8 hC = *(const u16x8*)(Y2 + (size_t)sC * 512 + lane * 8);
      for (int p = rs + 1; p < re; ++p) {
        int sNx = csr_s[p];
        float4 wN4 = w4[p];
        u16x8 hN = *(const u16x8*)(Y2 + (size_t)sNx * 512 + lane * 8);
        float w = kk == 0 ? wC4.x : kk == 1 ? wC4.y : kk == 2 ? wC4.z : wC4.w;
        #pragma unroll
        for (int j = 0; j < 8; ++j) a[j] += w * bf2f(hC[j]);
        wC4 = wN4; hC = hN;
      }
      float w = kk == 0 ? wC4.x : kk == 1 ? wC4.y : kk == 2 ? wC4.z : wC4.w;
      #pragma unroll
      for (int j = 0; j < 8; ++j) a[j] += w * bf2f(hC[j]);
    }
    #pragma unroll
    for (int j = 0; j < 8; ++j) {
      float z = dd * a[j] + bb[j];
      s[j] += z > 0.f ? z : 0.f;
    }
  }
  __shared__ float lsum[4 * 512];
  #pragma unroll
  for (int j = 0; j < 8; ++j) lsum[wv * 512 + kk * 128 + c0 + j] = s[j];
  __syncthreads();
  for (int i = threadIdx.x; i < 512; i += 256)
    atomicAdd(&colsum[i], lsum[i] + lsum[512 + i] + lsum[1024 + i] + lsum[1536 + i]);
}

// ---------- descriptors[k][o] = colsum_k/NN . fc_W + fc_b ----------
__global__ void desc_kernel(const float* __restrict__ colsum,
    const float* __restrict__ fcW, const float* __restrict__ fcb,
    float* __restrict__ out)
{
  int t = threadIdx.x;
  if (t >= 128) return;
  int k = t >> 5, o = t & 31;
  float acc = 0.f;
  for (int c = 0; c < 128; ++c)
    acc += colsum[k * 128 + c] * fcW[c * 32 + o];
  out[t] = acc * (1.f / (float)NN) + fcb[o];
}

extern "C" void kernel_launch(void* const* d_in, const int* in_sizes, int n_in,
                              void* d_out, int out_size, void* d_ws, size_t ws_size,
                              hipStream_t stream)
{
  (void)in_sizes; (void)n_in; (void)out_size; (void)ws_size;
  const float* X   = (const float*)d_in[0];
  const int*   ei  = (const int*)d_in[1];
  const float* Wh  = (const float*)d_in[2];
  const float* W1  = (const float*)d_in[3];
  const float* b1  = (const float*)d_in[4];
  const float* W2  = (const float*)d_in[5];
  const float* b2  = (const float*)d_in[6];
  const float* g1W = (const float*)d_in[7];
  const float* g1b = (const float*)d_in[8];
  const float* g2W = (const float*)d_in[9];
  const float* g2b = (const float*)d_in[10];
  const float* fcW = (const float*)d_in[11];
  const float* fcb = (const float*)d_in[12];
  float* out = (float*)d_out;

  char* ws = (char*)d_ws;
  size_t off = 0;
  auto alloc = [&](size_t bytes) -> void* {
    void* p = ws + off; off += (bytes + 255) & ~(size_t)255; return p;
  };
  unsigned short* WhT = (unsigned short*)alloc((size_t)128 * KPAD * 2);
  unsigned short* g1T = (unsigned short*)alloc((size_t)256 * 128 * 2);
  unsigned short* g2T = (unsigned short*)alloc((size_t)128 * 256 * 2);
  float* Wc  = (float*)alloc(2048 * 4);
  unsigned short* h0 = (unsigned short*)alloc((size_t)NN * 128 * 2);
  unsigned short* H1 = (unsigned short*)alloc((size_t)NN * 256 * 2);
  float* P   = (float*)alloc((size_t)NN * 16 * 4);
  float* deg = (float*)alloc((size_t)4 * NN * 4);     // [n][4]
  float* dinv= (float*)alloc((size_t)4 * NN * 4);     // [n][4]
  int* hist  = (int*)alloc((size_t)NN * 4);
  int* rowst = (int*)alloc((size_t)(NN + 1) * 4);
  int* cursor= (int*)alloc((size_t)NN * 4);
  int* bsum  = (int*)alloc(256 * 4);
  int* csr_s = (int*)alloc((size_t)NE * 4);
  float4* Gk4 = (float4*)alloc((size_t)NE * 16);
  float4* w4  = (float4*)alloc((size_t)NE * 16);
  unsigned short* Z1 = (unsigned short*)alloc((size_t)4 * NN * 256 * 2);  // [n][4][256]
  unsigned short* Y2 = (unsigned short*)alloc((size_t)4 * NN * 128 * 2);  // [n][4][128]
  float* colsum = (float*)alloc(512 * 4);

  float* GkOut = out + 128;
  const int gEdge = (NE + 255) / 256;
  const int gPrep = (128*KPAD + 256*128 + 128*256 + 2048 + 4*NN + 255) / 256;

  prep_kernel<<<gPrep, 256, 0, stream>>>(
      Wh, g1W, g2W, W1, WhT, g1T, g2T, Wc, deg, hist, colsum);
  gemm_kernel<1><<<dim3(391, 1), 256, 0, stream>>>(
      X, WhT, h0, NN, 128, INDIM, KPAD, KPAD / 64);
  gemm_kernel<0><<<dim3(391, 2), 256, 0, stream>>>(
      h0, g1T, H1, NN, 256, 128, 128, 2);
  p_kernel<<<196, 256, 0, stream>>>(h0, Wc, P);
  gk_kernel<<<gEdge, 256, 0, stream>>>(ei, P, b1, W2, b2, GkOut, Gk4, deg, hist);
  scan1_kernel<<<196, 256, 0, stream>>>(hist, rowst, bsum);
  scan2_kernel<<<1, 256, 0, stream>>>(bsum, 196);
  scan3_kernel<<<196, 256, 0, stream>>>(rowst, bsum, cursor,
      (const float4*)deg, (float4*)dinv);
  csr_kernel<<<gEdge, 256, 0, stream>>>(ei, cursor, Gk4, (const float4*)dinv,
      csr_s, w4);
  aggA_kernel<<<2048, 256, 0, stream>>>(H1, Z1, (const float4*)dinv, rowst, csr_s, w4, g1b);
  gemm_kernel<0><<<dim3(1563, 1), 256, 0, stream>>>(
      Z1, g2T, Y2, 4 * NN, 128, 256, 256, 4);
  aggB_kernel<<<2048, 256, 0, stream>>>(
      Y2, (const float4*)dinv, rowst, csr_s, w4, g2b, colsum);
  desc_kernel<<<1, 128, 0, stream>>>(colsum, fcW, fcb, out);
}